// Round 7
// baseline (108.473 us; speedup 1.0000x reference)
//
#include <hip/hip_runtime.h>
#include <hip/hip_fp16.h>

typedef __fp16 h2 __attribute__((ext_vector_type(2)));

#if defined(__has_builtin)
#if __has_builtin(__builtin_amdgcn_fdot2)
#define HAVE_FDOT2 1
#endif
#endif

__device__ inline float dot2f(h2 a, h2 b, float acc) {
#ifdef HAVE_FDOT2
    return __builtin_amdgcn_fdot2(a, b, acc, false);
#else
    return acc + (float)a.x * (float)b.x + (float)a.y * (float)b.y;
#endif
}

__device__ inline float wave_sum(float v) {
#pragma unroll
    for (int off = 32; off > 0; off >>= 1) v += __shfl_down(v, off, 64);
    return v;
}

// =============== Kernel 1: prep (1060 blocks x 256) ===============
// blk <1024   : feat group-stat partials (64 groups x 16 chunks)
// 1024..1027  : per-b full chain: dec4 GN+ReLU+GAP -> g -> x_feat -> F[153] -> F_ws
// 1028..1059  : E[c,o] = W_ctrl[o,256:512] . emb[c]
__global__ __launch_bounds__(256) void prep(
    const float* __restrict__ feat, const float* __restrict__ dec4,
    const float* __restrict__ gn_gap_gamma, const float* __restrict__ gn_gap_beta,
    const float* __restrict__ W_gap, const float* __restrict__ b_gap,
    const float* __restrict__ emb, const float* __restrict__ W_ctrl,
    const float* __restrict__ b_ctrl,
    float* __restrict__ partials, float* __restrict__ F_ws,
    float* __restrict__ E_ws) {
    int blk = blockIdx.x;
    int tid = threadIdx.x;
    if (blk < 1024) {
        int grp = blk >> 4;     // b*16+g
        int chunk = blk & 15;
        const float4* base = (const float4*)(feat + (size_t)grp * 262144 + (size_t)chunk * 16384);
        float s = 0.f, sq = 0.f;
#pragma unroll
        for (int i = 0; i < 16; ++i) {
            float4 v = base[i * 256 + tid];
            s += v.x + v.y + v.z + v.w;
            sq += v.x * v.x + v.y * v.y + v.z * v.z + v.w * v.w;
        }
        __shared__ float ls[4], lq[4];
        s = wave_sum(s); sq = wave_sum(sq);
        int wid = tid >> 6, lane = tid & 63;
        if (lane == 0) { ls[wid] = s; lq[wid] = sq; }
        __syncthreads();
        if (tid == 0) {
            partials[blk * 2 + 0] = ls[0] + ls[1] + ls[2] + ls[3];
            partials[blk * 2 + 1] = lq[0] + lq[1] + lq[2] + lq[3];
        }
    } else if (blk < 1028) {
        // ---- per-b: dec4 (512ch x 256px) GN+ReLU+GAP -> x_feat -> F ----
        int b = blk - 1024;
        const float* base = dec4 + (size_t)b * 131072;
        __shared__ float gL[512];
        __shared__ float xfL[256];
        int c0 = tid * 2;                       // this thread's 2 channels
        const float4* r0 = (const float4*)(base + c0 * 256);
        const float4* r1 = (const float4*)(base + (c0 + 1) * 256);
        // pass 1: per-channel sums -> group (32ch) stats via 16-lane reduce
        float s0 = 0.f, q0 = 0.f, s1 = 0.f, q1 = 0.f;
#pragma unroll 8
        for (int i = 0; i < 64; ++i) {
            float4 a = r0[i];
            s0 += a.x + a.y + a.z + a.w;
            q0 += a.x * a.x + a.y * a.y + a.z * a.z + a.w * a.w;
            float4 e = r1[i];
            s1 += e.x + e.y + e.z + e.w;
            q1 += e.x * e.x + e.y * e.y + e.z * e.z + e.w * e.w;
        }
        float s = s0 + s1, q = q0 + q1;
#pragma unroll
        for (int m = 1; m < 16; m <<= 1) {
            s += __shfl_xor(s, m, 64);
            q += __shfl_xor(q, m, 64);
        }
        const float inv = 1.f / 8192.f;
        float mu = s * inv;
        float var = q * inv - mu * mu;
        float rs = rsqrtf(var + 1e-5f);
        float sc0 = rs * gn_gap_gamma[c0], sh0 = gn_gap_beta[c0] - mu * sc0;
        float sc1 = rs * gn_gap_gamma[c0 + 1], sh1 = gn_gap_beta[c0 + 1] - mu * sc1;
        // pass 2 (L2-hot): relu + spatial mean
        float a0 = 0.f, a1 = 0.f;
#pragma unroll 8
        for (int i = 0; i < 64; ++i) {
            float4 v = r0[i];
            a0 += fmaxf(v.x * sc0 + sh0, 0.f) + fmaxf(v.y * sc0 + sh0, 0.f)
                + fmaxf(v.z * sc0 + sh0, 0.f) + fmaxf(v.w * sc0 + sh0, 0.f);
            float4 u = r1[i];
            a1 += fmaxf(u.x * sc1 + sh1, 0.f) + fmaxf(u.y * sc1 + sh1, 0.f)
                + fmaxf(u.z * sc1 + sh1, 0.f) + fmaxf(u.w * sc1 + sh1, 0.f);
        }
        gL[c0] = a0 * (1.f / 256.f);
        gL[c0 + 1] = a1 * (1.f / 256.f);
        __syncthreads();
        // x_feat = g @ W_gap.T + b_gap
        {
            float acc = b_gap[tid];
            const float4* w4 = (const float4*)(W_gap + tid * 512);
            const float4* g4 = (const float4*)gL;
#pragma unroll 8
            for (int k = 0; k < 128; ++k) {
                float4 a = w4[k], g = g4[k];
                acc += a.x * g.x + a.y * g.y + a.z * g.z + a.w * g.w;
            }
            xfL[tid] = acc;
        }
        __syncthreads();
        if (tid < 153) {
            float acc = b_ctrl[tid];
            const float4* w4 = (const float4*)(W_ctrl + tid * 512);
            const float4* x4 = (const float4*)xfL;
#pragma unroll 8
            for (int k = 0; k < 64; ++k) {
                float4 a = w4[k], x = x4[k];
                acc += a.x * x.x + a.y * x.y + a.z * x.z + a.w * x.w;
            }
            F_ws[b * 160 + tid] = acc;
        }
    } else {
        // ---- E[c,o] ----
        int c = blk - 1028;
        __shared__ float es[256];
        es[tid] = emb[c * 256 + tid];
        __syncthreads();
        if (tid < 153) {
            const float4* w4 = (const float4*)(W_ctrl + tid * 512 + 256);
            const float4* e4 = (const float4*)es;
            float acc = 0.f;
#pragma unroll 8
            for (int k = 0; k < 64; ++k) {
                float4 a = w4[k], e = e4[k];
                acc += a.x * e.x + a.y * e.y + a.z * e.z + a.w * e.w;
            }
            E_ws[c * 153 + tid] = acc;
        }
    }
}

// =============== Kernel 2: main (512 blocks x 512) ===============
// Block = (b, 512-px tile). 8 waves; wave w owns c in [4w, 4w+4).
// Params built in LDS from F_ws + E_ws (packed f16, 320 B per c).
__global__ __launch_bounds__(512, 4) void mainK(
    const float* __restrict__ feat, const float* __restrict__ partials,
    const float* __restrict__ gamma, const float* __restrict__ beta,
    const float* __restrict__ W_pre, const float* __restrict__ b_pre,
    const float* __restrict__ F_ws, const float* __restrict__ E_ws,
    float* __restrict__ out) {
    int blk = blockIdx.x;            // 0..511
    int b = blk >> 7;
    int tid = threadIdx.x;
    int w = tid >> 6, lane = tid & 63;
    int P0 = (blk & 127) << 9;

    __shared__ __align__(16) float smem[4768];  // 19072 B
    float4* pp   = (float4*)smem;               // [0,2560) packed params
    float4* hi_l = (float4*)(smem + 2560);      // [2560,4608) hi f16x8 per px
    float* scv = smem + 4608;                   // 64
    float* shv = smem + 4672;                   // 64
    float* mus = smem + 4736;                   // 16
    float* rss = smem + 4752;                   // 16

    // stage params: pk[c][o<152]=f16(F+E), byte304=f32 b3
    const float* Fb = F_ws + b * 160;
    for (int i = tid; i < 5120; i += 512) {
        int c = i / 160, o = i - c * 160;
        if (o < 152)
            ((__fp16*)smem)[c * 160 + o] = (__fp16)(Fb[o] + E_ws[c * 153 + o]);
        else if (o == 152)
            smem[c * 80 + 76] = Fb[152] + E_ws[c * 153 + 152];
    }
    if (tid < 16) {
        float s = 0.f, q = 0.f;
#pragma unroll
        for (int cc = 0; cc < 16; ++cc) {
            int idx = ((b * 16 + tid) * 16 + cc) * 2;
            s += partials[idx]; q += partials[idx + 1];
        }
        const float inv = 1.f / 262144.f;
        float mu = s * inv;
        float var = q * inv - mu * mu;
        mus[tid] = mu; rss[tid] = rsqrtf(var + 1e-5f);
    }
    __syncthreads();
    if (tid < 64) {
        float mu = mus[tid >> 2], rs = rss[tid >> 2];
        float sg = rs * gamma[tid];
        scv[tid] = sg;
        shv[tid] = beta[tid] - mu * sg;
    }
    __syncthreads();

    // head: 1 px per thread
    {
        float hi[8];
#pragma unroll
        for (int o = 0; o < 8; ++o) hi[o] = b_pre[o];
        const float* fb = feat + ((size_t)b << 22) + P0 + tid;
#pragma unroll
        for (int ch = 0; ch < 64; ++ch) {
            float v = fb[(size_t)ch << 16];
            float pre = fmaxf(v * scv[ch] + shv[ch], 0.f);
#pragma unroll
            for (int o = 0; o < 8; ++o) hi[o] += W_pre[o * 64 + ch] * pre;
        }
        float4 hq;
        hq.x = __builtin_bit_cast(float, __builtin_amdgcn_cvt_pkrtz(hi[0], hi[1]));
        hq.y = __builtin_bit_cast(float, __builtin_amdgcn_cvt_pkrtz(hi[2], hi[3]));
        hq.z = __builtin_bit_cast(float, __builtin_amdgcn_cvt_pkrtz(hi[4], hi[5]));
        hq.w = __builtin_bit_cast(float, __builtin_amdgcn_cvt_pkrtz(hi[6], hi[7]));
        hi_l[(tid >> 1) + (tid & 1) * 256] = hq;  // even-px | odd-px halves
    }
    __syncthreads();

    // MLP: wave w -> 4 c over all 512 px (256 pairs, 4 j-iters)
    float* ob = out + ((size_t)b << 21) + P0;
#pragma unroll 1
    for (int kk = 0; kk < 4; ++kk) {
        int c = (w << 2) + kk;
        const float4* Pc = pp + c * 20;
        float4 w1r[8], w2r[8];
#pragma unroll
        for (int o = 0; o < 8; ++o) w1r[o] = Pc[o];
#pragma unroll
        for (int o = 0; o < 8; ++o) w2r[o] = Pc[8 + o];
        float4 w3r = Pc[16];
        float4 b1r = Pc[17];
        float4 b2r = Pc[18];
        float b3v = Pc[19].x;
        float b1f[8], b2f[8];
        { h2 t = __builtin_bit_cast(h2, b1r.x); b1f[0] = t.x; b1f[1] = t.y; }
        { h2 t = __builtin_bit_cast(h2, b1r.y); b1f[2] = t.x; b1f[3] = t.y; }
        { h2 t = __builtin_bit_cast(h2, b1r.z); b1f[4] = t.x; b1f[5] = t.y; }
        { h2 t = __builtin_bit_cast(h2, b1r.w); b1f[6] = t.x; b1f[7] = t.y; }
        { h2 t = __builtin_bit_cast(h2, b2r.x); b2f[0] = t.x; b2f[1] = t.y; }
        { h2 t = __builtin_bit_cast(h2, b2r.y); b2f[2] = t.x; b2f[3] = t.y; }
        { h2 t = __builtin_bit_cast(h2, b2r.z); b2f[4] = t.x; b2f[5] = t.y; }
        { h2 t = __builtin_bit_cast(h2, b2r.w); b2f[6] = t.x; b2f[7] = t.y; }

        float* cp = ob + ((size_t)c << 16);
#pragma unroll
        for (int j = 0; j < 4; ++j) {
            int q = j * 64 + lane;   // pair index 0..255
            float4 ha = hi_l[q];
            float4 hb = hi_l[256 + q];
            h2 a0 = __builtin_bit_cast(h2, ha.x), a1 = __builtin_bit_cast(h2, ha.y),
               a2 = __builtin_bit_cast(h2, ha.z), a3 = __builtin_bit_cast(h2, ha.w);
            h2 e0 = __builtin_bit_cast(h2, hb.x), e1 = __builtin_bit_cast(h2, hb.y),
               e2 = __builtin_bit_cast(h2, hb.z), e3 = __builtin_bit_cast(h2, hb.w);

            float x1a[8], x1b[8];
#pragma unroll
            for (int o = 0; o < 8; ++o) {
                h2 wa = __builtin_bit_cast(h2, w1r[o].x), wb = __builtin_bit_cast(h2, w1r[o].y),
                   wc = __builtin_bit_cast(h2, w1r[o].z), wd = __builtin_bit_cast(h2, w1r[o].w);
                float s0 = dot2f(wd, a3, dot2f(wc, a2, dot2f(wb, a1, dot2f(wa, a0, b1f[o]))));
                float s1 = dot2f(wd, e3, dot2f(wc, e2, dot2f(wb, e1, dot2f(wa, e0, b1f[o]))));
                x1a[o] = fmaxf(s0, 0.f);
                x1b[o] = fmaxf(s1, 0.f);
            }
            h2 pa0 = __builtin_amdgcn_cvt_pkrtz(x1a[0], x1a[1]);
            h2 pa1 = __builtin_amdgcn_cvt_pkrtz(x1a[2], x1a[3]);
            h2 pa2 = __builtin_amdgcn_cvt_pkrtz(x1a[4], x1a[5]);
            h2 pa3 = __builtin_amdgcn_cvt_pkrtz(x1a[6], x1a[7]);
            h2 pb0 = __builtin_amdgcn_cvt_pkrtz(x1b[0], x1b[1]);
            h2 pb1 = __builtin_amdgcn_cvt_pkrtz(x1b[2], x1b[3]);
            h2 pb2 = __builtin_amdgcn_cvt_pkrtz(x1b[4], x1b[5]);
            h2 pb3 = __builtin_amdgcn_cvt_pkrtz(x1b[6], x1b[7]);

            float x2a[8], x2b[8];
#pragma unroll
            for (int o = 0; o < 8; ++o) {
                h2 wa = __builtin_bit_cast(h2, w2r[o].x), wb = __builtin_bit_cast(h2, w2r[o].y),
                   wc = __builtin_bit_cast(h2, w2r[o].z), wd = __builtin_bit_cast(h2, w2r[o].w);
                float s0 = dot2f(wd, pa3, dot2f(wc, pa2, dot2f(wb, pa1, dot2f(wa, pa0, b2f[o]))));
                float s1 = dot2f(wd, pb3, dot2f(wc, pb2, dot2f(wb, pb1, dot2f(wa, pb0, b2f[o]))));
                x2a[o] = fmaxf(s0, 0.f);
                x2b[o] = fmaxf(s1, 0.f);
            }
            h2 qa0 = __builtin_amdgcn_cvt_pkrtz(x2a[0], x2a[1]);
            h2 qa1 = __builtin_amdgcn_cvt_pkrtz(x2a[2], x2a[3]);
            h2 qa2 = __builtin_amdgcn_cvt_pkrtz(x2a[4], x2a[5]);
            h2 qa3 = __builtin_amdgcn_cvt_pkrtz(x2a[6], x2a[7]);
            h2 qb0 = __builtin_amdgcn_cvt_pkrtz(x2b[0], x2b[1]);
            h2 qb1 = __builtin_amdgcn_cvt_pkrtz(x2b[2], x2b[3]);
            h2 qb2 = __builtin_amdgcn_cvt_pkrtz(x2b[4], x2b[5]);
            h2 qb3 = __builtin_amdgcn_cvt_pkrtz(x2b[6], x2b[7]);

            h2 w3a = __builtin_bit_cast(h2, w3r.x), w3b = __builtin_bit_cast(h2, w3r.y),
               w3c = __builtin_bit_cast(h2, w3r.z), w3d = __builtin_bit_cast(h2, w3r.w);
            float lg0 = dot2f(w3d, qa3, dot2f(w3c, qa2, dot2f(w3b, qa1, dot2f(w3a, qa0, b3v))));
            float lg1 = dot2f(w3d, qb3, dot2f(w3c, qb2, dot2f(w3b, qb1, dot2f(w3a, qb0, b3v))));
            *(float2*)(cp + 2 * q) = make_float2(lg0, lg1);
        }
    }
}

// ---------------- launch ----------------
extern "C" void kernel_launch(void* const* d_in, const int* in_sizes, int n_in,
                              void* d_out, int out_size, void* d_ws, size_t ws_size,
                              hipStream_t stream) {
    const float* dec4         = (const float*)d_in[0];
    const float* feat         = (const float*)d_in[1];
    const float* gn_pre_gamma = (const float*)d_in[2];
    const float* gn_pre_beta  = (const float*)d_in[3];
    const float* W_pre        = (const float*)d_in[4];
    const float* b_pre        = (const float*)d_in[5];
    const float* gn_gap_gamma = (const float*)d_in[6];
    const float* gn_gap_beta  = (const float*)d_in[7];
    const float* W_gap        = (const float*)d_in[8];
    const float* b_gap        = (const float*)d_in[9];
    const float* emb          = (const float*)d_in[10];
    const float* W_ctrl       = (const float*)d_in[11];
    const float* b_ctrl       = (const float*)d_in[12];
    float* out = (float*)d_out;
    float* ws  = (float*)d_ws;

    float* partials = ws;            // 2048 floats
    float* F_ws     = ws + 2048;     // 640 (4 x 160)
    float* E_ws     = ws + 2688;     // 4896 (32 x 153)

    prep<<<1060, 256, 0, stream>>>(feat, dec4, gn_gap_gamma, gn_gap_beta,
                                   W_gap, b_gap, emb, W_ctrl, b_ctrl,
                                   partials, F_ws, E_ws);
    mainK<<<512, 512, 0, stream>>>(feat, partials, gn_pre_gamma, gn_pre_beta,
                                   W_pre, b_pre, F_ws, E_ws, out);
}

// Round 8
// 90.824 us; speedup vs baseline: 1.1943x; 1.1943x over previous
//
#include <hip/hip_runtime.h>
#include <hip/hip_fp16.h>

typedef __fp16 h2 __attribute__((ext_vector_type(2)));

#if defined(__has_builtin)
#if __has_builtin(__builtin_amdgcn_fdot2)
#define HAVE_FDOT2 1
#endif
#endif

__device__ inline float dot2f(h2 a, h2 b, float acc) {
#ifdef HAVE_FDOT2
    return __builtin_amdgcn_fdot2(a, b, acc, false);
#else
    return acc + (float)a.x * (float)b.x + (float)a.y * (float)b.y;
#endif
}

__device__ inline float wave_sum(float v) {
#pragma unroll
    for (int off = 32; off > 0; off >>= 1) v += __shfl_down(v, off, 64);
    return v;
}

// =============== Kernel 1: prep (608 blocks x 256) ===============
// blk <512   : feat group-stat partials (64 groups x 8 chunks of 32768 floats)
// 512..575   : dec4 GN+ReLU+GAP -> g_buf (one block per (b,gi), all-parallel)
// 576..607   : E[c,o] = W_ctrl[o,256:512] . emb[c]
__global__ __launch_bounds__(256) void prep(
    const float* __restrict__ feat, const float* __restrict__ dec4,
    const float* __restrict__ gn_gap_gamma, const float* __restrict__ gn_gap_beta,
    const float* __restrict__ emb, const float* __restrict__ W_ctrl,
    float* __restrict__ partials, float* __restrict__ g_buf,
    float* __restrict__ E_ws) {
    int blk = blockIdx.x;
    int tid = threadIdx.x;
    int wid = tid >> 6, lane = tid & 63;
    if (blk < 512) {
        int grp = blk >> 3;     // b*16+g
        int chunk = blk & 7;
        const float4* base = (const float4*)(feat + (size_t)grp * 262144 + (size_t)chunk * 32768);
        float sa = 0.f, qa = 0.f, sb = 0.f, qb = 0.f;
#pragma unroll 8
        for (int i = 0; i < 16; ++i) {
            float4 v = base[i * 256 + tid];
            float4 u = base[(i + 16) * 256 + tid];
            sa += v.x + v.y + v.z + v.w;
            qa += v.x * v.x + v.y * v.y + v.z * v.z + v.w * v.w;
            sb += u.x + u.y + u.z + u.w;
            qb += u.x * u.x + u.y * u.y + u.z * u.z + u.w * u.w;
        }
        __shared__ float ls[4], lq[4];
        float s = wave_sum(sa + sb);
        float q = wave_sum(qa + qb);
        if (lane == 0) { ls[wid] = s; lq[wid] = q; }
        __syncthreads();
        if (tid == 0) {
            partials[blk * 2 + 0] = ls[0] + ls[1] + ls[2] + ls[3];
            partials[blk * 2 + 1] = lq[0] + lq[1] + lq[2] + lq[3];
        }
    } else if (blk < 576) {
        // ---- dec4 group (b,gi): 32 ch x 256 px, fully parallel ----
        int idx = blk - 512;            // b*16+gi
        int b = idx >> 4, gi = idx & 15;
        const float* base = dec4 + (size_t)idx * 8192;
        int ch = tid >> 3, sub = tid & 7;     // thread: 32-px slice of channel ch
        const float4* r = (const float4*)(base + ch * 256 + sub * 32);
        float v[32];
        float s = 0.f, q = 0.f;
#pragma unroll
        for (int i = 0; i < 8; ++i) {
            float4 a = r[i];
            v[i * 4 + 0] = a.x; v[i * 4 + 1] = a.y; v[i * 4 + 2] = a.z; v[i * 4 + 3] = a.w;
            s += a.x + a.y + a.z + a.w;
            q += a.x * a.x + a.y * a.y + a.z * a.z + a.w * a.w;
        }
        __shared__ float ls[4], lq[4], bc[2];
        s = wave_sum(s); q = wave_sum(q);
        if (lane == 0) { ls[wid] = s; lq[wid] = q; }
        __syncthreads();
        if (tid == 0) {
            float S = ls[0] + ls[1] + ls[2] + ls[3];
            float Q = lq[0] + lq[1] + lq[2] + lq[3];
            const float inv = 1.f / 8192.f;
            float mu = S * inv;
            float var = Q * inv - mu * mu;
            bc[0] = mu;
            bc[1] = rsqrtf(var + 1e-5f);
        }
        __syncthreads();
        float mu = bc[0], rs = bc[1];
        int c = gi * 32 + ch;
        float sc = rs * gn_gap_gamma[c];
        float sh = gn_gap_beta[c] - mu * sc;
        float acc = 0.f;
#pragma unroll
        for (int i = 0; i < 32; ++i) acc += fmaxf(v[i] * sc + sh, 0.f);
#pragma unroll
        for (int m = 1; m < 8; m <<= 1) acc += __shfl_xor(acc, m, 64);
        if (sub == 0) g_buf[b * 512 + c] = acc * (1.f / 256.f);
    } else {
        // ---- E[c,o] ----
        int c = blk - 576;
        __shared__ float es[256];
        es[tid] = emb[c * 256 + tid];
        __syncthreads();
        if (tid < 153) {
            const float4* w4 = (const float4*)(W_ctrl + tid * 512 + 256);
            const float4* e4 = (const float4*)es;
            float acc = 0.f;
#pragma unroll 8
            for (int k = 0; k < 64; ++k) {
                float4 a = w4[k], e = e4[k];
                acc += a.x * e.x + a.y * e.y + a.z * e.z + a.w * e.w;
            }
            E_ws[c * 153 + tid] = acc;
        }
    }
}

// =============== Kernel 2: fc (4 blocks x 256) -> packed f16 params ===============
// Per (b,c), 320 bytes: f16[152] (W1|W2|W3|b1|b2), f32 b3 at byte 304.
__global__ __launch_bounds__(256) void fc(
    const float* __restrict__ g_buf, const float* __restrict__ W_gap,
    const float* __restrict__ b_gap, const float* __restrict__ W_ctrl,
    const float* __restrict__ b_ctrl, const float* __restrict__ E_ws,
    unsigned char* __restrict__ pk) {
    int b = blockIdx.x, tid = threadIdx.x;
    __shared__ float gs[512];
    __shared__ float xf[256];
    __shared__ float F[160];
    gs[tid] = g_buf[b * 512 + tid];
    gs[tid + 256] = g_buf[b * 512 + 256 + tid];
    __syncthreads();
    {
        const float4* w = (const float4*)(W_gap + tid * 512);
        const float4* g4 = (const float4*)gs;
        float acc = b_gap[tid];
#pragma unroll 8
        for (int k = 0; k < 128; ++k) {
            float4 wv = w[k], gv = g4[k];
            acc += wv.x * gv.x + wv.y * gv.y + wv.z * gv.z + wv.w * gv.w;
        }
        xf[tid] = acc;
    }
    __syncthreads();
    if (tid < 160) {
        float acc = 0.f;
        if (tid < 153) {
            const float4* w = (const float4*)(W_ctrl + tid * 512);
            const float4* x4 = (const float4*)xf;
#pragma unroll 8
            for (int k = 0; k < 64; ++k) {
                float4 wv = w[k], xv = x4[k];
                acc += wv.x * xv.x + wv.y * xv.y + wv.z * xv.z + wv.w * xv.w;
            }
            acc += b_ctrl[tid];
        }
        F[tid] = acc;
    }
    __syncthreads();
    unsigned char* dst = pk + (size_t)b * 10240;
    for (int c = 0; c < 32; ++c) {
        if (tid < 152) {
            float v = F[tid] + E_ws[c * 153 + tid];
            ((__fp16*)(dst + c * 320))[tid] = (__fp16)v;
        } else if (tid == 152) {
            *(float*)(dst + c * 320 + 304) = F[152] + E_ws[c * 153 + 152];
        }
    }
}

// =============== Kernel 3: mainK (512 blocks x 512, 8 waves) ===============
// Block = (b, 512-px tile). Wave w owns c in [4w, 4w+4).
__global__ __launch_bounds__(512, 4) void mainK(
    const float* __restrict__ feat, const float* __restrict__ partials,
    const float* __restrict__ gamma, const float* __restrict__ beta,
    const float* __restrict__ W_pre, const float* __restrict__ b_pre,
    const float4* __restrict__ pk, float* __restrict__ out) {
    int blk = blockIdx.x;            // 0..511
    int b = blk >> 7;
    int tid = threadIdx.x;
    int w = tid >> 6, lane = tid & 63;
    int P0 = (blk & 127) << 9;

    __shared__ __align__(16) float smem[4768];  // 19072 B
    float4* pp   = (float4*)smem;               // [0,2560) packed params
    float4* hi_l = (float4*)(smem + 2560);      // [2560,4608) hi f16x8 per px
    float* scv = smem + 4608;                   // 64
    float* shv = smem + 4672;                   // 64
    float* mus = smem + 4736;                   // 16
    float* rss = smem + 4752;                   // 16

    const float4* src = pk + (size_t)b * 640;
    for (int i = tid; i < 640; i += 512) pp[i] = src[i];

    if (tid < 16) {
        float s = 0.f, q = 0.f;
#pragma unroll
        for (int cc = 0; cc < 8; ++cc) {
            int idx = ((b * 16 + tid) * 8 + cc) * 2;
            s += partials[idx]; q += partials[idx + 1];
        }
        const float inv = 1.f / 262144.f;
        float mu = s * inv;
        float var = q * inv - mu * mu;
        mus[tid] = mu; rss[tid] = rsqrtf(var + 1e-5f);
    }
    __syncthreads();
    if (tid < 64) {
        float mu = mus[tid >> 2], rs = rss[tid >> 2];
        float sg = rs * gamma[tid];
        scv[tid] = sg;
        shv[tid] = beta[tid] - mu * sg;
    }
    __syncthreads();

    // head: 1 px per thread
    {
        float hi[8];
#pragma unroll
        for (int o = 0; o < 8; ++o) hi[o] = b_pre[o];
        const float* fb = feat + ((size_t)b << 22) + P0 + tid;
#pragma unroll
        for (int ch = 0; ch < 64; ++ch) {
            float v = fb[(size_t)ch << 16];
            float pre = fmaxf(v * scv[ch] + shv[ch], 0.f);
#pragma unroll
            for (int o = 0; o < 8; ++o) hi[o] += W_pre[o * 64 + ch] * pre;
        }
        float4 hq;
        hq.x = __builtin_bit_cast(float, __builtin_amdgcn_cvt_pkrtz(hi[0], hi[1]));
        hq.y = __builtin_bit_cast(float, __builtin_amdgcn_cvt_pkrtz(hi[2], hi[3]));
        hq.z = __builtin_bit_cast(float, __builtin_amdgcn_cvt_pkrtz(hi[4], hi[5]));
        hq.w = __builtin_bit_cast(float, __builtin_amdgcn_cvt_pkrtz(hi[6], hi[7]));
        hi_l[(tid >> 1) + (tid & 1) * 256] = hq;  // even-px | odd-px halves
    }
    __syncthreads();

    // MLP: wave w -> 4 c over all 512 px (256 pairs, 4 j-iters)
    float* ob = out + ((size_t)b << 21) + P0;
#pragma unroll 1
    for (int kk = 0; kk < 4; ++kk) {
        int c = (w << 2) + kk;
        const float4* Pc = pp + c * 20;
        float4 w1r[8], w2r[8];
#pragma unroll
        for (int o = 0; o < 8; ++o) w1r[o] = Pc[o];
#pragma unroll
        for (int o = 0; o < 8; ++o) w2r[o] = Pc[8 + o];
        float4 w3r = Pc[16];
        float4 b1r = Pc[17];
        float4 b2r = Pc[18];
        float b3v = Pc[19].x;
        float b1f[8], b2f[8];
        { h2 t = __builtin_bit_cast(h2, b1r.x); b1f[0] = t.x; b1f[1] = t.y; }
        { h2 t = __builtin_bit_cast(h2, b1r.y); b1f[2] = t.x; b1f[3] = t.y; }
        { h2 t = __builtin_bit_cast(h2, b1r.z); b1f[4] = t.x; b1f[5] = t.y; }
        { h2 t = __builtin_bit_cast(h2, b1r.w); b1f[6] = t.x; b1f[7] = t.y; }
        { h2 t = __builtin_bit_cast(h2, b2r.x); b2f[0] = t.x; b2f[1] = t.y; }
        { h2 t = __builtin_bit_cast(h2, b2r.y); b2f[2] = t.x; b2f[3] = t.y; }
        { h2 t = __builtin_bit_cast(h2, b2r.z); b2f[4] = t.x; b2f[5] = t.y; }
        { h2 t = __builtin_bit_cast(h2, b2r.w); b2f[6] = t.x; b2f[7] = t.y; }

        float* cp = ob + ((size_t)c << 16);
#pragma unroll
        for (int j = 0; j < 4; ++j) {
            int q = j * 64 + lane;   // pair index 0..255
            float4 ha = hi_l[q];
            float4 hb = hi_l[256 + q];
            h2 a0 = __builtin_bit_cast(h2, ha.x), a1 = __builtin_bit_cast(h2, ha.y),
               a2 = __builtin_bit_cast(h2, ha.z), a3 = __builtin_bit_cast(h2, ha.w);
            h2 e0 = __builtin_bit_cast(h2, hb.x), e1 = __builtin_bit_cast(h2, hb.y),
               e2 = __builtin_bit_cast(h2, hb.z), e3 = __builtin_bit_cast(h2, hb.w);

            float x1a[8], x1b[8];
#pragma unroll
            for (int o = 0; o < 8; ++o) {
                h2 wa = __builtin_bit_cast(h2, w1r[o].x), wb = __builtin_bit_cast(h2, w1r[o].y),
                   wc = __builtin_bit_cast(h2, w1r[o].z), wd = __builtin_bit_cast(h2, w1r[o].w);
                float s0 = dot2f(wd, a3, dot2f(wc, a2, dot2f(wb, a1, dot2f(wa, a0, b1f[o]))));
                float s1 = dot2f(wd, e3, dot2f(wc, e2, dot2f(wb, e1, dot2f(wa, e0, b1f[o]))));
                x1a[o] = fmaxf(s0, 0.f);
                x1b[o] = fmaxf(s1, 0.f);
            }
            h2 pa0 = __builtin_amdgcn_cvt_pkrtz(x1a[0], x1a[1]);
            h2 pa1 = __builtin_amdgcn_cvt_pkrtz(x1a[2], x1a[3]);
            h2 pa2 = __builtin_amdgcn_cvt_pkrtz(x1a[4], x1a[5]);
            h2 pa3 = __builtin_amdgcn_cvt_pkrtz(x1a[6], x1a[7]);
            h2 pb0 = __builtin_amdgcn_cvt_pkrtz(x1b[0], x1b[1]);
            h2 pb1 = __builtin_amdgcn_cvt_pkrtz(x1b[2], x1b[3]);
            h2 pb2 = __builtin_amdgcn_cvt_pkrtz(x1b[4], x1b[5]);
            h2 pb3 = __builtin_amdgcn_cvt_pkrtz(x1b[6], x1b[7]);

            float x2a[8], x2b[8];
#pragma unroll
            for (int o = 0; o < 8; ++o) {
                h2 wa = __builtin_bit_cast(h2, w2r[o].x), wb = __builtin_bit_cast(h2, w2r[o].y),
                   wc = __builtin_bit_cast(h2, w2r[o].z), wd = __builtin_bit_cast(h2, w2r[o].w);
                float s0 = dot2f(wd, pa3, dot2f(wc, pa2, dot2f(wb, pa1, dot2f(wa, pa0, b2f[o]))));
                float s1 = dot2f(wd, pb3, dot2f(wc, pb2, dot2f(wb, pb1, dot2f(wa, pb0, b2f[o]))));
                x2a[o] = fmaxf(s0, 0.f);
                x2b[o] = fmaxf(s1, 0.f);
            }
            h2 qa0 = __builtin_amdgcn_cvt_pkrtz(x2a[0], x2a[1]);
            h2 qa1 = __builtin_amdgcn_cvt_pkrtz(x2a[2], x2a[3]);
            h2 qa2 = __builtin_amdgcn_cvt_pkrtz(x2a[4], x2a[5]);
            h2 qa3 = __builtin_amdgcn_cvt_pkrtz(x2a[6], x2a[7]);
            h2 qb0 = __builtin_amdgcn_cvt_pkrtz(x2b[0], x2b[1]);
            h2 qb1 = __builtin_amdgcn_cvt_pkrtz(x2b[2], x2b[3]);
            h2 qb2 = __builtin_amdgcn_cvt_pkrtz(x2b[4], x2b[5]);
            h2 qb3 = __builtin_amdgcn_cvt_pkrtz(x2b[6], x2b[7]);

            h2 w3a = __builtin_bit_cast(h2, w3r.x), w3b = __builtin_bit_cast(h2, w3r.y),
               w3c = __builtin_bit_cast(h2, w3r.z), w3d = __builtin_bit_cast(h2, w3r.w);
            float lg0 = dot2f(w3d, qa3, dot2f(w3c, qa2, dot2f(w3b, qa1, dot2f(w3a, qa0, b3v))));
            float lg1 = dot2f(w3d, qb3, dot2f(w3c, qb2, dot2f(w3b, qb1, dot2f(w3a, qb0, b3v))));
            *(float2*)(cp + 2 * q) = make_float2(lg0, lg1);
        }
    }
}

// ---------------- launch ----------------
extern "C" void kernel_launch(void* const* d_in, const int* in_sizes, int n_in,
                              void* d_out, int out_size, void* d_ws, size_t ws_size,
                              hipStream_t stream) {
    const float* dec4         = (const float*)d_in[0];
    const float* feat         = (const float*)d_in[1];
    const float* gn_pre_gamma = (const float*)d_in[2];
    const float* gn_pre_beta  = (const float*)d_in[3];
    const float* W_pre        = (const float*)d_in[4];
    const float* b_pre        = (const float*)d_in[5];
    const float* gn_gap_gamma = (const float*)d_in[6];
    const float* gn_gap_beta  = (const float*)d_in[7];
    const float* W_gap        = (const float*)d_in[8];
    const float* b_gap        = (const float*)d_in[9];
    const float* emb          = (const float*)d_in[10];
    const float* W_ctrl       = (const float*)d_in[11];
    const float* b_ctrl       = (const float*)d_in[12];
    float* out = (float*)d_out;
    float* ws  = (float*)d_ws;

    float* partials = ws;            // 1024 floats (512 x 2)
    float* g_buf    = ws + 1024;     // 2048
    float* E_ws     = ws + 3072;     // 4896
    unsigned char* pkB = (unsigned char*)(ws + 7968);  // 40960 B (16B-aligned)

    prep<<<608, 256, 0, stream>>>(feat, dec4, gn_gap_gamma, gn_gap_beta,
                                  emb, W_ctrl, partials, g_buf, E_ws);
    fc<<<4, 256, 0, stream>>>(g_buf, W_gap, b_gap, W_ctrl, b_ctrl, E_ws, pkB);
    mainK<<<512, 512, 0, stream>>>(feat, partials, gn_pre_gamma, gn_pre_beta,
                                   W_pre, b_pre, (const float4*)pkB, out);
}